// Round 3
// baseline (114.951 us; speedup 1.0000x reference)
//
#include <hip/hip_runtime.h>
#include <math.h>

#define NPRED 16384
#define NGT   32768
#define BETA  0.45f
#define GAMMA 0.45f

#define BLOCK 256
#define PPT   8                                // preds per thread
#define PRED_PER_BLOCK (BLOCK * PPT)           // 2048
#define PRED_CHUNKS (NPRED / PRED_PER_BLOCK)   // 8
#define SLAB  256                              // gt rows per block (fits L1, j fits 8 bits)
#define NSLAB (NGT / SLAB)                     // 128

// ---------------------------------------------------------------------------
// prep: h[j] = (-2gx, -2gy, -2gz, |g|^2) so d = fma(px,hx,fma(py,hy,fma(pz,hz,hw)))
// ---------------------------------------------------------------------------
__global__ __launch_bounds__(BLOCK) void prep_kernel(
    const float* __restrict__ gt_data, float4* __restrict__ h)
{
    const int j = blockIdx.x * BLOCK + threadIdx.x;
    if (j < NGT) {
        const float x = gt_data[j * 6 + 0];
        const float y = gt_data[j * 6 + 1];
        const float z = gt_data[j * 6 + 2];
        h[j] = make_float4(-2.0f * x, -2.0f * y, -2.0f * z,
                           fmaf(x, x, fmaf(y, y, z * z)));
    }
}

// ---------------------------------------------------------------------------
// nn: no LDS, no barrier. gt slab (4KB) is read via uniform-address loads
// (L1/scalar-cache resident). Index packed into low 8 mantissa bits of d:
//   key = (bits(d) & 0xFFFFFF00) | j      (monotone within 2^-16 relative)
// reduced with fminf -> v_min_f32 / v_min3_f32. Per pair: 3 fma + and_or + ~0.5 min3.
// Cross-slab merge: u64 atomicMin on sortable(quantized d) << 32 | global_idx.
// ---------------------------------------------------------------------------
__global__ __launch_bounds__(BLOCK) void nn_kernel(
    const float* __restrict__ pred_feat,
    const float4* __restrict__ h,
    unsigned long long* __restrict__ packed)
{
    const int chunk   = blockIdx.x;
    const int gt_base = blockIdx.y * SLAB;
    const int t       = threadIdx.x;

    float px[PPT], py[PPT], pz[PPT], kmin[PPT];

    const int pred_base = chunk * PRED_PER_BLOCK + t;
#pragma unroll
    for (int p = 0; p < PPT; ++p) {
        const int i = pred_base + p * BLOCK;
        px[p] = pred_feat[i * 6 + 0];
        py[p] = pred_feat[i * 6 + 1];
        pz[p] = pred_feat[i * 6 + 2];
        kmin[p] = INFINITY;
    }

#pragma unroll 2
    for (int j = 0; j < SLAB; j += 2) {
        const float4 g0 = h[gt_base + j];
        const float4 g1 = h[gt_base + j + 1];
#pragma unroll
        for (int p = 0; p < PPT; ++p) {
            const float d0 = fmaf(px[p], g0.x, fmaf(py[p], g0.y, fmaf(pz[p], g0.z, g0.w)));
            const float d1 = fmaf(px[p], g1.x, fmaf(py[p], g1.y, fmaf(pz[p], g1.z, g1.w)));
            const float k0 = __uint_as_float((__float_as_uint(d0) & 0xFFFFFF00u) | (unsigned)j);
            const float k1 = __uint_as_float((__float_as_uint(d1) & 0xFFFFFF00u) | (unsigned)(j + 1));
            kmin[p] = fminf(kmin[p], fminf(k0, k1));   // -> v_min3_f32
        }
    }

#pragma unroll
    for (int p = 0; p < PPT; ++p) {
        const int i = pred_base + p * BLOCK;
        const unsigned int bits = __float_as_uint(kmin[p]);
        const unsigned int jloc = bits & 0xFFu;
        const unsigned int dq   = bits & 0xFFFFFF00u;      // quantized distance
        const unsigned int key  = (dq & 0x80000000u) ? ~dq : (dq | 0x80000000u);
        const unsigned long long pk =
            ((unsigned long long)key << 32) | (unsigned int)(gt_base + jloc);
        atomicMin(&packed[i], pk);
    }
}

// ---------------------------------------------------------------------------
// finalize: gather normals at argmin, mean(1 - cos), plus regularizer term.
// ---------------------------------------------------------------------------
__global__ __launch_bounds__(BLOCK) void finalize_kernel(
    const float* __restrict__ pred_feat,
    const float* __restrict__ gt_data,
    const float* __restrict__ Rm,
    const float* __restrict__ tv,
    const float* __restrict__ sv,
    const unsigned long long* __restrict__ packed,
    float* __restrict__ out)
{
    const int i = blockIdx.x * BLOCK + threadIdx.x;
    float c = 0.0f;
    if (i < NPRED) {
        const unsigned long long pk = packed[i];
        const int idx = (int)(pk & 0xFFFFFFFFull);
        const float nx = pred_feat[i * 6 + 3];
        const float ny = pred_feat[i * 6 + 4];
        const float nz = pred_feat[i * 6 + 5];
        const float gx = gt_data[idx * 6 + 3];
        const float gy = gt_data[idx * 6 + 4];
        const float gz = gt_data[idx * 6 + 5];
        const float pn = fmaxf(sqrtf(fmaf(nx, nx, fmaf(ny, ny, nz * nz))), 1e-12f);
        const float gn = fmaxf(sqrtf(fmaf(gx, gx, fmaf(gy, gy, gz * gz))), 1e-12f);
        const float cosv = fmaf(nx, gx, fmaf(ny, gy, nz * gz)) / (pn * gn);
        c = 1.0f - cosv;
    }
#pragma unroll
    for (int off = 32; off > 0; off >>= 1) c += __shfl_down(c, off, 64);
    if ((threadIdx.x & 63) == 0) atomicAdd(out, c * (GAMMA / (float)NPRED));

    if (blockIdx.x == 0 && threadIdx.x == 0) {
        float rs = 0.0f;
#pragma unroll
        for (int k = 0; k < 9; ++k) {
            const float v = Rm[k] - ((k % 4 == 0) ? 1.0f : 0.0f);
            rs = fmaf(v, v, rs);
        }
        const float rot = sqrtf(rs);
        const float tr  = sqrtf(fmaf(tv[0], tv[0], fmaf(tv[1], tv[1], tv[2] * tv[2])));
        const float sc  = (sv[0] - 1.0f) * (sv[0] - 1.0f);
        atomicAdd(out, BETA * (rot + tr + sc));
    }
}

extern "C" void kernel_launch(void* const* d_in, const int* in_sizes, int n_in,
                              void* d_out, int out_size, void* d_ws, size_t ws_size,
                              hipStream_t stream)
{
    const float* pred = (const float*)d_in[0];
    const float* gt   = (const float*)d_in[1];
    const float* Rm   = (const float*)d_in[2];
    const float* tv   = (const float*)d_in[3];
    const float* sv   = (const float*)d_in[4];
    float* out = (float*)d_out;

    unsigned long long* packed = (unsigned long long*)d_ws;              // 128 KB
    float4* h = (float4*)((char*)d_ws + NPRED * sizeof(unsigned long long)); // 512 KB

    hipMemsetAsync(packed, 0xFF, NPRED * sizeof(unsigned long long), stream);
    hipMemsetAsync(out, 0, sizeof(float), stream);

    prep_kernel<<<NGT / BLOCK, BLOCK, 0, stream>>>(gt, h);
    dim3 grid(PRED_CHUNKS, NSLAB);
    nn_kernel<<<grid, BLOCK, 0, stream>>>(pred, h, packed);
    finalize_kernel<<<NPRED / BLOCK, BLOCK, 0, stream>>>(pred, gt, Rm, tv, sv, packed, out);
}

// Round 4
// 66.298 us; speedup vs baseline: 1.7339x; 1.7339x over previous
//
#include <hip/hip_runtime.h>
#include <math.h>

#define NPRED 16384
#define NGT   32768
#define BETA  0.45f
#define GAMMA 0.45f

#define BLOCK 256
#define PPT   8                                // preds per thread
#define PRED_PER_BLOCK (BLOCK * PPT)           // 2048
#define PRED_CHUNKS (NPRED / PRED_PER_BLOCK)   // 8
#define SLAB  256                              // gt rows per block; j fits 8 bits
#define NSLAB (NGT / SLAB)                     // 128

// ---------------------------------------------------------------------------
// nn: LDS-broadcast slab + packed-key min reduction.
//   LDS holds h = (-2gx,-2gy,-2gz,|g|^2); d = fma(px,hx,fma(py,hy,fma(pz,hz,hw)))
//   key = (bits(d) & 0xFFFFFF00) | j   -- one v_and_or_b32 (mask in SGPR, j in VGPR)
//   reduce with v_min3_f32 (2 keys + running min in one instr)
// Per pair: 3 fma + 1 and_or + 0.5 min3 ~= 4.6 VALU ops.
// Cross-slab merge: u64 atomicMin on sortable(quantized d) << 32 | global_idx.
// ---------------------------------------------------------------------------
__global__ __launch_bounds__(BLOCK) void nn_kernel(
    const float* __restrict__ pred_feat,
    const float* __restrict__ gt_data,
    unsigned long long* __restrict__ packed)
{
    __shared__ float4 hs[SLAB];

    const int chunk   = blockIdx.x;
    const int gt_base = blockIdx.y * SLAB;
    const int t       = threadIdx.x;

    // Stage slab (SLAB == BLOCK: one row per thread)
    {
        const int gj = gt_base + t;
        const float x = gt_data[gj * 6 + 0];
        const float y = gt_data[gj * 6 + 1];
        const float z = gt_data[gj * 6 + 2];
        hs[t] = make_float4(-2.0f * x, -2.0f * y, -2.0f * z,
                            fmaf(x, x, fmaf(y, y, z * z)));
    }
    __syncthreads();

    float px[PPT], py[PPT], pz[PPT], kmin[PPT];
    const int pred_base = chunk * PRED_PER_BLOCK + t;
#pragma unroll
    for (int p = 0; p < PPT; ++p) {
        const int i = pred_base + p * BLOCK;
        px[p] = pred_feat[i * 6 + 0];
        py[p] = pred_feat[i * 6 + 1];
        pz[p] = pred_feat[i * 6 + 2];
        kmin[p] = INFINITY;
    }

    const unsigned int mask = 0xFFFFFF00u;   // lives in an SGPR
#pragma unroll 2
    for (int j = 0; j < SLAB; j += 2) {
        const float4 g0 = hs[j];       // broadcast: all lanes same addr, no conflict
        const float4 g1 = hs[j + 1];
        const int j0 = j, j1 = j + 1;
#pragma unroll
        for (int p = 0; p < PPT; ++p) {
            const float d0 = fmaf(px[p], g0.x, fmaf(py[p], g0.y, fmaf(pz[p], g0.z, g0.w)));
            const float d1 = fmaf(px[p], g1.x, fmaf(py[p], g1.y, fmaf(pz[p], g1.z, g1.w)));
            float k0, k1;
            asm("v_and_or_b32 %0, %1, %2, %3" : "=v"(k0) : "v"(d0), "s"(mask), "v"(j0));
            asm("v_and_or_b32 %0, %1, %2, %3" : "=v"(k1) : "v"(d1), "s"(mask), "v"(j1));
            asm("v_min3_f32 %0, %1, %2, %3"
                : "=v"(kmin[p]) : "v"(kmin[p]), "v"(k0), "v"(k1));
        }
    }

#pragma unroll
    for (int p = 0; p < PPT; ++p) {
        const int i = pred_base + p * BLOCK;
        const unsigned int bits = __float_as_uint(kmin[p]);
        const unsigned int jloc = bits & 0xFFu;
        const unsigned int dq   = bits & 0xFFFFFF00u;      // quantized distance
        const unsigned int key  = (dq & 0x80000000u) ? ~dq : (dq | 0x80000000u);
        const unsigned long long pk =
            ((unsigned long long)key << 32) | (unsigned int)(gt_base + jloc);
        atomicMin(&packed[i], pk);
    }
}

// ---------------------------------------------------------------------------
// finalize: gather normals at argmin, mean(1 - cos), plus regularizer term.
// ---------------------------------------------------------------------------
__global__ __launch_bounds__(BLOCK) void finalize_kernel(
    const float* __restrict__ pred_feat,
    const float* __restrict__ gt_data,
    const float* __restrict__ Rm,
    const float* __restrict__ tv,
    const float* __restrict__ sv,
    const unsigned long long* __restrict__ packed,
    float* __restrict__ out)
{
    const int i = blockIdx.x * BLOCK + threadIdx.x;
    float c = 0.0f;
    if (i < NPRED) {
        const unsigned long long pk = packed[i];
        const int idx = (int)(pk & 0xFFFFFFFFull);
        const float nx = pred_feat[i * 6 + 3];
        const float ny = pred_feat[i * 6 + 4];
        const float nz = pred_feat[i * 6 + 5];
        const float gx = gt_data[idx * 6 + 3];
        const float gy = gt_data[idx * 6 + 4];
        const float gz = gt_data[idx * 6 + 5];
        const float pn = fmaxf(sqrtf(fmaf(nx, nx, fmaf(ny, ny, nz * nz))), 1e-12f);
        const float gn = fmaxf(sqrtf(fmaf(gx, gx, fmaf(gy, gy, gz * gz))), 1e-12f);
        const float cosv = fmaf(nx, gx, fmaf(ny, gy, nz * gz)) / (pn * gn);
        c = 1.0f - cosv;
    }
#pragma unroll
    for (int off = 32; off > 0; off >>= 1) c += __shfl_down(c, off, 64);
    if ((threadIdx.x & 63) == 0) atomicAdd(out, c * (GAMMA / (float)NPRED));

    if (blockIdx.x == 0 && threadIdx.x == 0) {
        float rs = 0.0f;
#pragma unroll
        for (int k = 0; k < 9; ++k) {
            const float v = Rm[k] - ((k % 4 == 0) ? 1.0f : 0.0f);
            rs = fmaf(v, v, rs);
        }
        const float rot = sqrtf(rs);
        const float tr  = sqrtf(fmaf(tv[0], tv[0], fmaf(tv[1], tv[1], tv[2] * tv[2])));
        const float sc  = (sv[0] - 1.0f) * (sv[0] - 1.0f);
        atomicAdd(out, BETA * (rot + tr + sc));
    }
}

extern "C" void kernel_launch(void* const* d_in, const int* in_sizes, int n_in,
                              void* d_out, int out_size, void* d_ws, size_t ws_size,
                              hipStream_t stream)
{
    const float* pred = (const float*)d_in[0];
    const float* gt   = (const float*)d_in[1];
    const float* Rm   = (const float*)d_in[2];
    const float* tv   = (const float*)d_in[3];
    const float* sv   = (const float*)d_in[4];
    float* out = (float*)d_out;
    unsigned long long* packed = (unsigned long long*)d_ws;

    hipMemsetAsync(packed, 0xFF, NPRED * sizeof(unsigned long long), stream);
    hipMemsetAsync(out, 0, sizeof(float), stream);

    dim3 grid(PRED_CHUNKS, NSLAB);
    nn_kernel<<<grid, BLOCK, 0, stream>>>(pred, gt, packed);
    finalize_kernel<<<NPRED / BLOCK, BLOCK, 0, stream>>>(pred, gt, Rm, tv, sv, packed, out);
}